// Round 20
// baseline (762.250 us; speedup 1.0000x reference)
//
#include <hip/hip_runtime.h>
#include <hip/hip_bf16.h>

#define NN 50000
#define EE 1600000
#define NEDGE (EE + NN)   // with self loops
#define HH 4
#define HC 128
#define GG 64
#define GMT 64            // nodes per standalone gemm block
#define GMT2 32           // nodes per merged-gemm block
#define NBKT 196          // dst buckets of 256 nodes
#define BCAP 12544        // pairs capacity per bucket (mean 8163, +48 sigma)
#define BKE 2048          // edges per bucketize block
#define NB1 ((EE + BKE - 1) / BKE)          // 782
#define GB ((NN + GMT - 1) / GMT)           // 782

__device__ __forceinline__ float lrelu(float x) { return fmaxf(x, 0.2f * x); }

__device__ __forceinline__ unsigned packbf2(float a, float b) {
    unsigned ua = __float_as_uint(a);
    ua = (ua + 0x7fffu + ((ua >> 16) & 1u)) >> 16;
    unsigned ub = __float_as_uint(b);
    ub = (ub + 0x7fffu + ((ub >> 16) & 1u)) >> 16;
    return ua | (ub << 16);
}

__global__ __launch_bounds__(256) void binit(int* __restrict__ bcur) {
    int t = blockIdx.x * 256 + threadIdx.x;
    if (t < NBKT) bcur[t] = t * BCAP;
}

// ---------------- merged dispatch: 3-way split ----------------
// bid%3 in {0,1}: gemm half-tile (32 nodes); bid%3==2: bucketize.
// pairs packed 4B: (d<<16)|s  (both < 65536).
__global__ __launch_bounds__(256) void g0bkt(
    const float* __restrict__ X, const float* __restrict__ W,
    const float* __restrict__ a_src, const float* __restrict__ a_dst,
    unsigned* __restrict__ xwb, float* __restrict__ as_, float* __restrict__ ad_,
    const int* __restrict__ ei, int* __restrict__ bcur, unsigned* __restrict__ pairs) {
    __shared__ union U {
        float xs[GMT2][HC + 4];                       // 16.9 KB
        struct {
            int cnt[NBKT], off[NBKT], gbase[NBKT];    // 2.4 KB
            int wsum[4], woff[4];
            unsigned stage[BKE];                      // 8 KB
        } b;
    } u;
    int t = threadIdx.x;
    int id = (int)(blockIdx.x / 3);
    int type = (int)(blockIdx.x % 3);

    if (type < 2) {
        // ---------------- gemm branch (32-node half-tile) ----------------
        int n0 = (id * 2 + type) * GMT2;
        for (int i = t; i < GMT2 * (HC / 4); i += 256) {
            int r = i >> 5, c4 = i & 31;
            int n = n0 + r;
            float4 v = (n < NN) ? ((const float4*)X)[(size_t)n * 32 + c4]
                                : make_float4(0.f, 0.f, 0.f, 0.f);
            *(float4*)&u.xs[r][c4 * 4] = v;
        }
        __syncthreads();
        int jg = t & 31;
        int ng = t >> 5;      // 8 node groups x 4 nodes
        float4 acc[4] = {};
        for (int k = 0; k < HC; k += 4) {
            float4 wr[4];
#pragma unroll
            for (int dk = 0; dk < 4; ++dk) wr[dk] = ((const float4*)W)[(k + dk) * 32 + jg];
#pragma unroll
            for (int r = 0; r < 4; ++r) {
                float4 xv = *(const float4*)&u.xs[ng * 4 + r][k];
                acc[r].x = fmaf(xv.x, wr[0].x, acc[r].x);
                acc[r].y = fmaf(xv.x, wr[0].y, acc[r].y);
                acc[r].z = fmaf(xv.x, wr[0].z, acc[r].z);
                acc[r].w = fmaf(xv.x, wr[0].w, acc[r].w);
                acc[r].x = fmaf(xv.y, wr[1].x, acc[r].x);
                acc[r].y = fmaf(xv.y, wr[1].y, acc[r].y);
                acc[r].z = fmaf(xv.y, wr[1].z, acc[r].z);
                acc[r].w = fmaf(xv.y, wr[1].w, acc[r].w);
                acc[r].x = fmaf(xv.z, wr[2].x, acc[r].x);
                acc[r].y = fmaf(xv.z, wr[2].y, acc[r].y);
                acc[r].z = fmaf(xv.z, wr[2].z, acc[r].z);
                acc[r].w = fmaf(xv.z, wr[2].w, acc[r].w);
                acc[r].x = fmaf(xv.w, wr[3].x, acc[r].x);
                acc[r].y = fmaf(xv.w, wr[3].y, acc[r].y);
                acc[r].z = fmaf(xv.w, wr[3].z, acc[r].z);
                acc[r].w = fmaf(xv.w, wr[3].w, acc[r].w);
            }
        }
        float4 asv = ((const float4*)a_src)[jg];
        float4 adv = ((const float4*)a_dst)[jg];
#pragma unroll
        for (int r = 0; r < 4; ++r) {
            int n = n0 + ng * 4 + r;
            float ps = acc[r].x * asv.x + acc[r].y * asv.y + acc[r].z * asv.z + acc[r].w * asv.w;
            float pd = acc[r].x * adv.x + acc[r].y * adv.y + acc[r].z * adv.z + acc[r].w * adv.w;
            ps += __shfl_xor(ps, 1); pd += __shfl_xor(pd, 1);
            ps += __shfl_xor(ps, 2); pd += __shfl_xor(pd, 2);
            ps += __shfl_xor(ps, 4); pd += __shfl_xor(pd, 4);
            if (n < NN) {
                ((uint2*)xwb)[(size_t)n * 32 + jg] =
                    make_uint2(packbf2(acc[r].x, acc[r].y), packbf2(acc[r].z, acc[r].w));
                if ((jg & 7) == 0) {
                    int h = jg >> 3;
                    as_[n * HH + h] = ps;
                    ad_[n * HH + h] = pd;
                }
            }
        }
    } else {
        // ---------------- bucketize branch ----------------
        int e0 = id * BKE;
        int n = EE - e0; if (n > BKE) n = BKE;
        for (int i = t; i < NBKT; i += 256) u.b.cnt[i] = 0;
        __syncthreads();
        unsigned dv[8], sv[8];
        int rk[8];
#pragma unroll
        for (int k = 0; k < 8; ++k) {
            int i = t + k * 256;
            if (i < n) {
                dv[k] = (unsigned)ei[EE + e0 + i];
                sv[k] = (unsigned)ei[e0 + i];
                rk[k] = atomicAdd(&u.b.cnt[dv[k] >> 8], 1);
            }
        }
        __syncthreads();
        {
            int v = (t < NBKT) ? u.b.cnt[t] : 0;
            int lane = t & 63, wv = t >> 6;
            int x = v;
#pragma unroll
            for (int o = 1; o < 64; o <<= 1) { int y = __shfl_up(x, o); if (lane >= o) x += y; }
            if (lane == 63) u.b.wsum[wv] = x;
            __syncthreads();
            if (t == 0) { int r = 0; for (int k2 = 0; k2 < 4; ++k2) { u.b.woff[k2] = r; r += u.b.wsum[k2]; } }
            __syncthreads();
            if (t < NBKT) u.b.off[t] = x - v + u.b.woff[wv];
        }
        __syncthreads();
#pragma unroll
        for (int k = 0; k < 8; ++k) {
            int i = t + k * 256;
            if (i < n) u.b.stage[u.b.off[dv[k] >> 8] + rk[k]] = (dv[k] << 16) | sv[k];
        }
        __syncthreads();
        if (t < NBKT) { int c = u.b.cnt[t]; u.b.gbase[t] = c ? atomicAdd(&bcur[t], c) : 0; }
        __syncthreads();
        for (int i = t; i < n; i += 256) {
            unsigned pr = u.b.stage[i];
            int b = (int)(pr >> 24);
            pairs[(size_t)u.b.gbase[b] + (i - u.b.off[b])] = pr;
        }
    }
}

// ---------------- debucket (computes its own bucket base) ----------------
__global__ __launch_bounds__(512) void debucket(const unsigned* __restrict__ pairs,
                                                const int* __restrict__ bcur,
                                                int* __restrict__ row_start,
                                                int* __restrict__ esrc) {
    __shared__ int cnt[256], off[256], cur[256];
    __shared__ int wsum[4], woff[4];
    __shared__ int wred[8];
    __shared__ int stage[BCAP + 256];
    int b = blockIdx.x, t = threadIdx.x;
    int n0 = b * 256;
    int nnode = NN - n0; if (nnode > 256) nnode = 256;
    int pcnt = bcur[b] - b * BCAP;

    int base;
    {
        int v = 0;
        if (t < b) {
            int pc = bcur[t] - t * BCAP;
            int nd = (t < NBKT - 1) ? 256 : (NN - (NBKT - 1) * 256);
            v = pc + nd;
        }
        int lane = t & 63, wv = t >> 6;
#pragma unroll
        for (int o = 1; o < 64; o <<= 1) v += __shfl_xor(v, o);
        if (lane == 0) wred[wv] = v;
        __syncthreads();
        if (t == 0) { int s = 0; for (int k = 0; k < 8; ++k) s += wred[k]; wred[0] = s; }
        __syncthreads();
        base = wred[0];
    }
    __syncthreads();
    if (t < 256) cnt[t] = 0;
    __syncthreads();
    for (int i = t; i < pcnt; i += 512)
        atomicAdd(&cnt[(pairs[(size_t)b * BCAP + i] >> 16) & 255u], 1);
    __syncthreads();
    {
        int v = 0, x = 0;
        int lane = t & 63, wv = t >> 6;
        if (t < 256) {
            v = cnt[t] + (t < nnode ? 1 : 0);
            x = v;
#pragma unroll
            for (int o = 1; o < 64; o <<= 1) { int y = __shfl_up(x, o); if (lane >= o) x += y; }
            if (lane == 63) wsum[wv] = x;
        }
        __syncthreads();
        if (t == 0) { int r = 0; for (int k = 0; k < 4; ++k) { woff[k] = r; r += wsum[k]; } }
        __syncthreads();
        if (t < 256) off[t] = x - v + woff[wv];
    }
    __syncthreads();
    if (t < nnode) {
        int o = off[t];
        stage[o] = n0 + t;
        cur[t] = o + 1;
        row_start[n0 + t] = base + o;
    }
    __syncthreads();
    for (int i = t; i < pcnt; i += 512) {
        unsigned pr = pairs[(size_t)b * BCAP + i];
        int p = atomicAdd(&cur[(pr >> 16) & 255u], 1);
        stage[p] = (int)(pr & 0xFFFFu);
    }
    __syncthreads();
    int tot = pcnt + nnode;
    for (int i = t; i < tot; i += 512) esrc[base + i] = stage[i];
    if (b == NBKT - 1 && t == 0) row_start[NN] = NEDGE;
}

// ---------------- GEMM (X @ W) + per-head alpha dots (layer 1) ----------------
__global__ __launch_bounds__(256) void gemm_alpha(
    const float* __restrict__ X, const float* __restrict__ W,
    const float* __restrict__ a_src, const float* __restrict__ a_dst,
    unsigned* __restrict__ xwb, float* __restrict__ as_, float* __restrict__ ad_) {
    __shared__ float xs[GMT][HC + 4];
    int tid = threadIdx.x;
    int n0 = blockIdx.x * GMT;
    for (int i = tid; i < GMT * (HC / 4); i += 256) {
        int r = i >> 5, c4 = i & 31;
        int n = n0 + r;
        float4 v = (n < NN) ? ((const float4*)X)[(size_t)n * 32 + c4]
                            : make_float4(0.f, 0.f, 0.f, 0.f);
        *(float4*)&xs[r][c4 * 4] = v;
    }
    __syncthreads();

    int jg = tid & 31;
    int ng = tid >> 5;
    float4 acc[8] = {};
    for (int k = 0; k < HC; k += 4) {
        float4 wr[4];
#pragma unroll
        for (int dk = 0; dk < 4; ++dk) wr[dk] = ((const float4*)W)[(k + dk) * 32 + jg];
#pragma unroll
        for (int r = 0; r < 8; ++r) {
            float4 xv = *(const float4*)&xs[ng * 8 + r][k];
            acc[r].x = fmaf(xv.x, wr[0].x, acc[r].x);
            acc[r].y = fmaf(xv.x, wr[0].y, acc[r].y);
            acc[r].z = fmaf(xv.x, wr[0].z, acc[r].z);
            acc[r].w = fmaf(xv.x, wr[0].w, acc[r].w);
            acc[r].x = fmaf(xv.y, wr[1].x, acc[r].x);
            acc[r].y = fmaf(xv.y, wr[1].y, acc[r].y);
            acc[r].z = fmaf(xv.y, wr[1].z, acc[r].z);
            acc[r].w = fmaf(xv.y, wr[1].w, acc[r].w);
            acc[r].x = fmaf(xv.z, wr[2].x, acc[r].x);
            acc[r].y = fmaf(xv.z, wr[2].y, acc[r].y);
            acc[r].z = fmaf(xv.z, wr[2].z, acc[r].z);
            acc[r].w = fmaf(xv.z, wr[2].w, acc[r].w);
            acc[r].x = fmaf(xv.w, wr[3].x, acc[r].x);
            acc[r].y = fmaf(xv.w, wr[3].y, acc[r].y);
            acc[r].z = fmaf(xv.w, wr[3].z, acc[r].z);
            acc[r].w = fmaf(xv.w, wr[3].w, acc[r].w);
        }
    }
    float4 asv = ((const float4*)a_src)[jg];
    float4 adv = ((const float4*)a_dst)[jg];
#pragma unroll
    for (int r = 0; r < 8; ++r) {
        int n = n0 + ng * 8 + r;
        float ps = acc[r].x * asv.x + acc[r].y * asv.y + acc[r].z * asv.z + acc[r].w * asv.w;
        float pd = acc[r].x * adv.x + acc[r].y * adv.y + acc[r].z * adv.z + acc[r].w * adv.w;
        ps += __shfl_xor(ps, 1); pd += __shfl_xor(pd, 1);
        ps += __shfl_xor(ps, 2); pd += __shfl_xor(pd, 2);
        ps += __shfl_xor(ps, 4); pd += __shfl_xor(pd, 4);
        if (n < NN) {
            ((uint2*)xwb)[(size_t)n * 32 + jg] =
                make_uint2(packbf2(acc[r].x, acc[r].y), packbf2(acc[r].z, acc[r].w));
            if ((jg & 7) == 0) {
                int h = jg >> 3;
                as_[n * HH + h] = ps;
                ad_[n * HH + h] = pd;
            }
        }
    }
}

// ---------------- fused segment softmax + aggregate + bias + ELU ----------------
// do_pool==0: write out[node]; do_pool==1: skip the h-write and atomically
// accumulate the pooled sums (global_mean_pool fused into the epilogue).
#define SWSTR 66
__global__ __launch_bounds__(256) void aggregate(
    const int* __restrict__ esrc, const int* __restrict__ row_start,
    const float* __restrict__ as_, const float* __restrict__ ad_,
    const unsigned* __restrict__ xwb, const float* __restrict__ bias,
    float* __restrict__ out,
    const int* __restrict__ batch, float* __restrict__ sums,
    float* __restrict__ cnts, int do_pool) {
    __shared__ float2 sw_all[4][4 * SWSTR];
    int wid = (int)(threadIdx.x >> 6);
    int node = blockIdx.x * 4 + wid;
    if (node >= NN) return;
    int lane = threadIdx.x & 63;
    float2* sw = &sw_all[wid][0];
    int beg = row_start[node];
    int end = row_start[node + 1];
    float4 ad = ((const float4*)ad_)[node];

    int sub = lane >> 4;
    int c8 = lane & 15;
    int h = c8 >> 2;
    const char* xwp = (const char*)xwb + (c8 << 4);
    const char* asp = (const char*)as_;
    float4 accA = make_float4(0.f, 0.f, 0.f, 0.f);
    float4 accB = make_float4(0.f, 0.f, 0.f, 0.f);
    float dloc = 0.f;

    for (int base = beg; base < end; base += 64) {
        int i = base + lane;
        int cnt = end - base; if (cnt > 64) cnt = 64;
        if (i < end) {
            int s = esrc[i];
            float4 av = *(const float4*)(asp + ((unsigned)s << 4));
            float w0 = __expf(lrelu(av.x + ad.x));
            float w1 = __expf(lrelu(av.y + ad.y));
            float w2 = __expf(lrelu(av.z + ad.z));
            float w3 = __expf(lrelu(av.w + ad.w));
            float sf = __int_as_float(s);
            sw[0 * SWSTR + lane] = make_float2(sf, w0);
            sw[1 * SWSTR + lane] = make_float2(sf, w1);
            sw[2 * SWSTR + lane] = make_float2(sf, w2);
            sw[3 * SWSTR + lane] = make_float2(sf, w3);
        }
        int iters = (cnt + 3) >> 2;
        bool ok = sub < cnt;
        float2 sv = sw[h * SWSTR + (ok ? sub : 0)];
        float wj = ok ? sv.y : 0.f;
        unsigned row = ok ? ((unsigned)__float_as_int(sv.x) << 8) : 0u;
        uint4 v = *(const uint4*)(xwp + row);
        for (int it = 1; it <= iters; ++it) {
            int j1 = (it << 2) + sub;
            bool ok1 = j1 < cnt;
            float2 sv1 = sw[h * SWSTR + (ok1 ? j1 : 0)];
            float w1 = ok1 ? sv1.y : 0.f;
            unsigned row1 = ok1 ? ((unsigned)__float_as_int(sv1.x) << 8) : 0u;
            uint4 v1 = *(const uint4*)(xwp + row1);
            dloc += wj;
            accA.x = fmaf(wj, __uint_as_float(v.x << 16), accA.x);
            accA.y = fmaf(wj, __uint_as_float(v.x & 0xffff0000u), accA.y);
            accA.z = fmaf(wj, __uint_as_float(v.y << 16), accA.z);
            accA.w = fmaf(wj, __uint_as_float(v.y & 0xffff0000u), accA.w);
            accB.x = fmaf(wj, __uint_as_float(v.z << 16), accB.x);
            accB.y = fmaf(wj, __uint_as_float(v.z & 0xffff0000u), accB.y);
            accB.z = fmaf(wj, __uint_as_float(v.w << 16), accB.z);
            accB.w = fmaf(wj, __uint_as_float(v.w & 0xffff0000u), accB.w);
            v = v1; wj = w1;
        }
    }
#pragma unroll
    for (int off = 16; off <= 32; off <<= 1) {
        accA.x += __shfl_xor(accA.x, off);
        accA.y += __shfl_xor(accA.y, off);
        accA.z += __shfl_xor(accA.z, off);
        accA.w += __shfl_xor(accA.w, off);
        accB.x += __shfl_xor(accB.x, off);
        accB.y += __shfl_xor(accB.y, off);
        accB.z += __shfl_xor(accB.z, off);
        accB.w += __shfl_xor(accB.w, off);
        dloc += __shfl_xor(dloc, off);
    }
    if (sub == 0) {
        float inv = 1.f / dloc;
        float4 bb0 = ((const float4*)bias)[c8 * 2];
        float4 bb1 = ((const float4*)bias)[c8 * 2 + 1];
        float4 oA, oB;
        oA.x = fmaf(accA.x, inv, bb0.x);
        oA.y = fmaf(accA.y, inv, bb0.y);
        oA.z = fmaf(accA.z, inv, bb0.z);
        oA.w = fmaf(accA.w, inv, bb0.w);
        oB.x = fmaf(accB.x, inv, bb1.x);
        oB.y = fmaf(accB.y, inv, bb1.y);
        oB.z = fmaf(accB.z, inv, bb1.z);
        oB.w = fmaf(accB.w, inv, bb1.w);
        oA.x = oA.x > 0.f ? oA.x : expm1f(oA.x);
        oA.y = oA.y > 0.f ? oA.y : expm1f(oA.y);
        oA.z = oA.z > 0.f ? oA.z : expm1f(oA.z);
        oA.w = oA.w > 0.f ? oA.w : expm1f(oA.w);
        oB.x = oB.x > 0.f ? oB.x : expm1f(oB.x);
        oB.y = oB.y > 0.f ? oB.y : expm1f(oB.y);
        oB.z = oB.z > 0.f ? oB.z : expm1f(oB.z);
        oB.w = oB.w > 0.f ? oB.w : expm1f(oB.w);
        if (do_pool) {
            int g = batch[node];
            float* sg = sums + (size_t)g * HC + c8 * 8;
            atomicAdd(sg + 0, oA.x);
            atomicAdd(sg + 1, oA.y);
            atomicAdd(sg + 2, oA.z);
            atomicAdd(sg + 3, oA.w);
            atomicAdd(sg + 4, oB.x);
            atomicAdd(sg + 5, oB.y);
            atomicAdd(sg + 6, oB.z);
            atomicAdd(sg + 7, oB.w);
            if (c8 == 0) atomicAdd(&cnts[g], 1.0f);
        } else {
            ((float4*)out)[(size_t)node * 32 + c8 * 2] = oA;
            ((float4*)out)[(size_t)node * 32 + c8 * 2 + 1] = oB;
        }
    }
}

// ---------------- head ----------------
__global__ __launch_bounds__(128) void head_out(
    const float* __restrict__ sums, const float* __restrict__ cnts,
    const float* __restrict__ lin_w, const float* __restrict__ lin_b,
    float* __restrict__ out) {
    int g = blockIdx.x;
    int j = threadIdx.x;
    float c = cnts[g];
    c = c > 1.f ? c : 1.f;
    float v = sums[g * HC + j] / c * lin_w[j];
    __shared__ float red[HC];
    red[j] = v;
    __syncthreads();
    for (int off = 64; off > 0; off >>= 1) {
        if (j < off) red[j] += red[j + off];
        __syncthreads();
    }
    if (j == 0) out[g] = red[0] + lin_b[0];
}

extern "C" void kernel_launch(void* const* d_in, const int* in_sizes, int n_in,
                              void* d_out, int out_size, void* d_ws, size_t ws_size,
                              hipStream_t stream) {
    const float* x   = (const float*)d_in[0];
    const int*   ei  = (const int*)d_in[1];
    const int*   bat = (const int*)d_in[2];
    const float* W0  = (const float*)d_in[3];
    const float* as0 = (const float*)d_in[4];
    const float* ad0 = (const float*)d_in[5];
    const float* b0  = (const float*)d_in[6];
    const float* W1  = (const float*)d_in[7];
    const float* as1 = (const float*)d_in[8];
    const float* ad1 = (const float*)d_in[9];
    const float* b1  = (const float*)d_in[10];
    const float* lw  = (const float*)d_in[11];
    const float* lb  = (const float*)d_in[12];
    float* out = (float*)d_out;

    char* w = (char*)d_ws;
    unsigned* xwb = (unsigned*)w; w += (size_t)NN * HC * 2;   // 12.8 MB bf16
    float* h0  = (float*)w;  w += (size_t)NN * HC * 4;        // 25.6 MB
    float* as_ = (float*)w;  w += (size_t)NN * HH * 4;
    float* ad_ = (float*)w;  w += (size_t)NN * HH * 4;
    int* row_start = (int*)w; w += (size_t)(NN + 1) * 4;
    int* bcur      = (int*)w; w += (size_t)NBKT * 4;
    int* esrc      = (int*)w; w += (size_t)NEDGE * 4;         // 6.6 MB
    unsigned* pairs = (unsigned*)w; w += (size_t)NBKT * BCAP * 4; // 9.8 MB
    float* sums = (float*)w; w += (size_t)GG * HC * 4;
    float* cnts = (float*)w; w += (size_t)GG * 4;

    const int ab = (NN + 3) / 4;

    // ---- init + merged {gemm L0 || bucketize} ----
    hipMemsetAsync(sums, 0, ((size_t)GG * HC + GG) * 4, stream);
    binit<<<1, 256, 0, stream>>>(bcur);
    g0bkt<<<NB1 * 3, 256, 0, stream>>>(x, W0, as0, ad0, xwb, as_, ad_,
                                       ei, bcur, pairs);
    debucket<<<NBKT, 512, 0, stream>>>(pairs, bcur, row_start, esrc);

    // ---- layer 0 aggregate ----
    aggregate<<<ab, 256, 0, stream>>>(esrc, row_start, as_, ad_, xwb, b0, h0,
                                      bat, sums, cnts, 0);

    // ---- layer 1 (pool fused into aggregate epilogue) ----
    gemm_alpha<<<GB, 256, 0, stream>>>(h0, W1, as1, ad1, xwb, as_, ad_);
    aggregate<<<ab, 256, 0, stream>>>(esrc, row_start, as_, ad_, xwb, b1, h0,
                                      bat, sums, cnts, 1);

    // ---- head ----
    head_out<<<GG, 128, 0, stream>>>(sums, cnts, lw, lb, out);
}

// Round 21
// 247.245 us; speedup vs baseline: 3.0830x; 3.0830x over previous
//
#include <hip/hip_runtime.h>
#include <hip/hip_bf16.h>

#define NN 50000
#define EE 1600000
#define NEDGE (EE + NN)   // with self loops
#define HH 4
#define HC 128
#define GG 64
#define GMT 64            // nodes per standalone gemm block
#define GMT2 32           // nodes per merged-gemm block
#define NBKT 196          // dst buckets of 256 nodes
#define BCAP 12544        // pairs capacity per bucket (mean 8163, +48 sigma)
#define BKE 2048          // edges per bucketize block
#define NB1 ((EE + BKE - 1) / BKE)          // 782
#define GB ((NN + GMT - 1) / GMT)           // 782

__device__ __forceinline__ float lrelu(float x) { return fmaxf(x, 0.2f * x); }

__device__ __forceinline__ unsigned packbf2(float a, float b) {
    unsigned ua = __float_as_uint(a);
    ua = (ua + 0x7fffu + ((ua >> 16) & 1u)) >> 16;
    unsigned ub = __float_as_uint(b);
    ub = (ub + 0x7fffu + ((ub >> 16) & 1u)) >> 16;
    return ua | (ub << 16);
}

__global__ __launch_bounds__(256) void binit(int* __restrict__ bcur) {
    int t = blockIdx.x * 256 + threadIdx.x;
    if (t < NBKT) bcur[t] = t * BCAP;
}

// ---------------- merged dispatch: 3-way split ----------------
// bid%3 in {0,1}: gemm half-tile (32 nodes); bid%3==2: bucketize.
// pairs packed 4B: (d<<16)|s  (both < 65536).
__global__ __launch_bounds__(256) void g0bkt(
    const float* __restrict__ X, const float* __restrict__ W,
    const float* __restrict__ a_src, const float* __restrict__ a_dst,
    unsigned* __restrict__ xwb, float* __restrict__ as_, float* __restrict__ ad_,
    const int* __restrict__ ei, int* __restrict__ bcur, unsigned* __restrict__ pairs) {
    __shared__ union U {
        float xs[GMT2][HC + 4];                       // 16.9 KB
        struct {
            int cnt[NBKT], off[NBKT], gbase[NBKT];    // 2.4 KB
            int wsum[4], woff[4];
            unsigned stage[BKE];                      // 8 KB
        } b;
    } u;
    int t = threadIdx.x;
    int id = (int)(blockIdx.x / 3);
    int type = (int)(blockIdx.x % 3);

    if (type < 2) {
        // ---------------- gemm branch (32-node half-tile) ----------------
        int n0 = (id * 2 + type) * GMT2;
        for (int i = t; i < GMT2 * (HC / 4); i += 256) {
            int r = i >> 5, c4 = i & 31;
            int n = n0 + r;
            float4 v = (n < NN) ? ((const float4*)X)[(size_t)n * 32 + c4]
                                : make_float4(0.f, 0.f, 0.f, 0.f);
            *(float4*)&u.xs[r][c4 * 4] = v;
        }
        __syncthreads();
        int jg = t & 31;
        int ng = t >> 5;      // 8 node groups x 4 nodes
        float4 acc[4] = {};
        for (int k = 0; k < HC; k += 4) {
            float4 wr[4];
#pragma unroll
            for (int dk = 0; dk < 4; ++dk) wr[dk] = ((const float4*)W)[(k + dk) * 32 + jg];
#pragma unroll
            for (int r = 0; r < 4; ++r) {
                float4 xv = *(const float4*)&u.xs[ng * 4 + r][k];
                acc[r].x = fmaf(xv.x, wr[0].x, acc[r].x);
                acc[r].y = fmaf(xv.x, wr[0].y, acc[r].y);
                acc[r].z = fmaf(xv.x, wr[0].z, acc[r].z);
                acc[r].w = fmaf(xv.x, wr[0].w, acc[r].w);
                acc[r].x = fmaf(xv.y, wr[1].x, acc[r].x);
                acc[r].y = fmaf(xv.y, wr[1].y, acc[r].y);
                acc[r].z = fmaf(xv.y, wr[1].z, acc[r].z);
                acc[r].w = fmaf(xv.y, wr[1].w, acc[r].w);
                acc[r].x = fmaf(xv.z, wr[2].x, acc[r].x);
                acc[r].y = fmaf(xv.z, wr[2].y, acc[r].y);
                acc[r].z = fmaf(xv.z, wr[2].z, acc[r].z);
                acc[r].w = fmaf(xv.z, wr[2].w, acc[r].w);
                acc[r].x = fmaf(xv.w, wr[3].x, acc[r].x);
                acc[r].y = fmaf(xv.w, wr[3].y, acc[r].y);
                acc[r].z = fmaf(xv.w, wr[3].z, acc[r].z);
                acc[r].w = fmaf(xv.w, wr[3].w, acc[r].w);
            }
        }
        float4 asv = ((const float4*)a_src)[jg];
        float4 adv = ((const float4*)a_dst)[jg];
#pragma unroll
        for (int r = 0; r < 4; ++r) {
            int n = n0 + ng * 4 + r;
            float ps = acc[r].x * asv.x + acc[r].y * asv.y + acc[r].z * asv.z + acc[r].w * asv.w;
            float pd = acc[r].x * adv.x + acc[r].y * adv.y + acc[r].z * adv.z + acc[r].w * adv.w;
            ps += __shfl_xor(ps, 1); pd += __shfl_xor(pd, 1);
            ps += __shfl_xor(ps, 2); pd += __shfl_xor(pd, 2);
            ps += __shfl_xor(ps, 4); pd += __shfl_xor(pd, 4);
            if (n < NN) {
                ((uint2*)xwb)[(size_t)n * 32 + jg] =
                    make_uint2(packbf2(acc[r].x, acc[r].y), packbf2(acc[r].z, acc[r].w));
                if ((jg & 7) == 0) {
                    int h = jg >> 3;
                    as_[n * HH + h] = ps;
                    ad_[n * HH + h] = pd;
                }
            }
        }
    } else {
        // ---------------- bucketize branch ----------------
        int e0 = id * BKE;
        int n = EE - e0; if (n > BKE) n = BKE;
        for (int i = t; i < NBKT; i += 256) u.b.cnt[i] = 0;
        __syncthreads();
        unsigned dv[8], sv[8];
        int rk[8];
#pragma unroll
        for (int k = 0; k < 8; ++k) {
            int i = t + k * 256;
            if (i < n) {
                dv[k] = (unsigned)ei[EE + e0 + i];
                sv[k] = (unsigned)ei[e0 + i];
                rk[k] = atomicAdd(&u.b.cnt[dv[k] >> 8], 1);
            }
        }
        __syncthreads();
        {
            int v = (t < NBKT) ? u.b.cnt[t] : 0;
            int lane = t & 63, wv = t >> 6;
            int x = v;
#pragma unroll
            for (int o = 1; o < 64; o <<= 1) { int y = __shfl_up(x, o); if (lane >= o) x += y; }
            if (lane == 63) u.b.wsum[wv] = x;
            __syncthreads();
            if (t == 0) { int r = 0; for (int k2 = 0; k2 < 4; ++k2) { u.b.woff[k2] = r; r += u.b.wsum[k2]; } }
            __syncthreads();
            if (t < NBKT) u.b.off[t] = x - v + u.b.woff[wv];
        }
        __syncthreads();
#pragma unroll
        for (int k = 0; k < 8; ++k) {
            int i = t + k * 256;
            if (i < n) u.b.stage[u.b.off[dv[k] >> 8] + rk[k]] = (dv[k] << 16) | sv[k];
        }
        __syncthreads();
        if (t < NBKT) { int c = u.b.cnt[t]; u.b.gbase[t] = c ? atomicAdd(&bcur[t], c) : 0; }
        __syncthreads();
        for (int i = t; i < n; i += 256) {
            unsigned pr = u.b.stage[i];
            int b = (int)(pr >> 24);   // d>>8 == (pr>>16)>>8
            pairs[(size_t)u.b.gbase[b] + (i - u.b.off[b])] = pr;
        }
    }
}

// ---------------- debucket (computes its own bucket base) ----------------
__global__ __launch_bounds__(512) void debucket(const unsigned* __restrict__ pairs,
                                                const int* __restrict__ bcur,
                                                int* __restrict__ row_start,
                                                int* __restrict__ esrc) {
    __shared__ int cnt[256], off[256], cur[256];
    __shared__ int wsum[4], woff[4];
    __shared__ int wred[8];
    __shared__ int stage[BCAP + 256];
    int b = blockIdx.x, t = threadIdx.x;
    int n0 = b * 256;
    int nnode = NN - n0; if (nnode > 256) nnode = 256;
    int pcnt = bcur[b] - b * BCAP;

    int base;
    {
        int v = 0;
        if (t < b) {
            int pc = bcur[t] - t * BCAP;
            int nd = (t < NBKT - 1) ? 256 : (NN - (NBKT - 1) * 256);
            v = pc + nd;
        }
        int lane = t & 63, wv = t >> 6;
#pragma unroll
        for (int o = 1; o < 64; o <<= 1) v += __shfl_xor(v, o);
        if (lane == 0) wred[wv] = v;
        __syncthreads();
        if (t == 0) { int s = 0; for (int k = 0; k < 8; ++k) s += wred[k]; wred[0] = s; }
        __syncthreads();
        base = wred[0];
    }
    __syncthreads();
    if (t < 256) cnt[t] = 0;
    __syncthreads();
    for (int i = t; i < pcnt; i += 512)
        atomicAdd(&cnt[(pairs[(size_t)b * BCAP + i] >> 16) & 255u], 1);
    __syncthreads();
    {
        int v = 0, x = 0;
        int lane = t & 63, wv = t >> 6;
        if (t < 256) {
            v = cnt[t] + (t < nnode ? 1 : 0);
            x = v;
#pragma unroll
            for (int o = 1; o < 64; o <<= 1) { int y = __shfl_up(x, o); if (lane >= o) x += y; }
            if (lane == 63) wsum[wv] = x;
        }
        __syncthreads();
        if (t == 0) { int r = 0; for (int k = 0; k < 4; ++k) { woff[k] = r; r += wsum[k]; } }
        __syncthreads();
        if (t < 256) off[t] = x - v + woff[wv];
    }
    __syncthreads();
    if (t < nnode) {
        int o = off[t];
        stage[o] = n0 + t;
        cur[t] = o + 1;
        row_start[n0 + t] = base + o;
    }
    __syncthreads();
    for (int i = t; i < pcnt; i += 512) {
        unsigned pr = pairs[(size_t)b * BCAP + i];
        int p = atomicAdd(&cur[(pr >> 16) & 255u], 1);
        stage[p] = (int)(pr & 0xFFFFu);
    }
    __syncthreads();
    int tot = pcnt + nnode;
    for (int i = t; i < tot; i += 512) esrc[base + i] = stage[i];
    if (b == NBKT - 1 && t == 0) row_start[NN] = NEDGE;
}

// ---------------- GEMM (X @ W) + per-head alpha dots (layer 1) ----------------
__global__ __launch_bounds__(256) void gemm_alpha(
    const float* __restrict__ X, const float* __restrict__ W,
    const float* __restrict__ a_src, const float* __restrict__ a_dst,
    unsigned* __restrict__ xwb, float* __restrict__ as_, float* __restrict__ ad_) {
    __shared__ float xs[GMT][HC + 4];
    int tid = threadIdx.x;
    int n0 = blockIdx.x * GMT;
    for (int i = tid; i < GMT * (HC / 4); i += 256) {
        int r = i >> 5, c4 = i & 31;
        int n = n0 + r;
        float4 v = (n < NN) ? ((const float4*)X)[(size_t)n * 32 + c4]
                            : make_float4(0.f, 0.f, 0.f, 0.f);
        *(float4*)&xs[r][c4 * 4] = v;
    }
    __syncthreads();

    int jg = tid & 31;
    int ng = tid >> 5;
    float4 acc[8] = {};
    for (int k = 0; k < HC; k += 4) {
        float4 wr[4];
#pragma unroll
        for (int dk = 0; dk < 4; ++dk) wr[dk] = ((const float4*)W)[(k + dk) * 32 + jg];
#pragma unroll
        for (int r = 0; r < 8; ++r) {
            float4 xv = *(const float4*)&xs[ng * 8 + r][k];
            acc[r].x = fmaf(xv.x, wr[0].x, acc[r].x);
            acc[r].y = fmaf(xv.x, wr[0].y, acc[r].y);
            acc[r].z = fmaf(xv.x, wr[0].z, acc[r].z);
            acc[r].w = fmaf(xv.x, wr[0].w, acc[r].w);
            acc[r].x = fmaf(xv.y, wr[1].x, acc[r].x);
            acc[r].y = fmaf(xv.y, wr[1].y, acc[r].y);
            acc[r].z = fmaf(xv.y, wr[1].z, acc[r].z);
            acc[r].w = fmaf(xv.y, wr[1].w, acc[r].w);
            acc[r].x = fmaf(xv.z, wr[2].x, acc[r].x);
            acc[r].y = fmaf(xv.z, wr[2].y, acc[r].y);
            acc[r].z = fmaf(xv.z, wr[2].z, acc[r].z);
            acc[r].w = fmaf(xv.z, wr[2].w, acc[r].w);
            acc[r].x = fmaf(xv.w, wr[3].x, acc[r].x);
            acc[r].y = fmaf(xv.w, wr[3].y, acc[r].y);
            acc[r].z = fmaf(xv.w, wr[3].z, acc[r].z);
            acc[r].w = fmaf(xv.w, wr[3].w, acc[r].w);
        }
    }
    float4 asv = ((const float4*)a_src)[jg];
    float4 adv = ((const float4*)a_dst)[jg];
#pragma unroll
    for (int r = 0; r < 8; ++r) {
        int n = n0 + ng * 8 + r;
        float ps = acc[r].x * asv.x + acc[r].y * asv.y + acc[r].z * asv.z + acc[r].w * asv.w;
        float pd = acc[r].x * adv.x + acc[r].y * adv.y + acc[r].z * adv.z + acc[r].w * adv.w;
        ps += __shfl_xor(ps, 1); pd += __shfl_xor(pd, 1);
        ps += __shfl_xor(ps, 2); pd += __shfl_xor(pd, 2);
        ps += __shfl_xor(ps, 4); pd += __shfl_xor(pd, 4);
        if (n < NN) {
            ((uint2*)xwb)[(size_t)n * 32 + jg] =
                make_uint2(packbf2(acc[r].x, acc[r].y), packbf2(acc[r].z, acc[r].w));
            if ((jg & 7) == 0) {
                int h = jg >> 3;
                as_[n * HH + h] = ps;
                ad_[n * HH + h] = pd;
            }
        }
    }
}

// ---------------- fused segment softmax + aggregate + bias + ELU ----------------
#define SWSTR 66
__global__ __launch_bounds__(256) void aggregate(
    const int* __restrict__ esrc, const int* __restrict__ row_start,
    const float* __restrict__ as_, const float* __restrict__ ad_,
    const unsigned* __restrict__ xwb, const float* __restrict__ bias,
    float* __restrict__ out) {
    __shared__ float2 sw_all[4][4 * SWSTR];
    int wid = (int)(threadIdx.x >> 6);
    int node = blockIdx.x * 4 + wid;
    if (node >= NN) return;
    int lane = threadIdx.x & 63;
    float2* sw = &sw_all[wid][0];
    int beg = row_start[node];
    int end = row_start[node + 1];
    float4 ad = ((const float4*)ad_)[node];

    int sub = lane >> 4;
    int c8 = lane & 15;
    int h = c8 >> 2;
    const char* xwp = (const char*)xwb + (c8 << 4);
    const char* asp = (const char*)as_;
    float4 accA = make_float4(0.f, 0.f, 0.f, 0.f);
    float4 accB = make_float4(0.f, 0.f, 0.f, 0.f);
    float dloc = 0.f;

    for (int base = beg; base < end; base += 64) {
        int i = base + lane;
        int cnt = end - base; if (cnt > 64) cnt = 64;
        if (i < end) {
            int s = esrc[i];
            float4 av = *(const float4*)(asp + ((unsigned)s << 4));
            float w0 = __expf(lrelu(av.x + ad.x));
            float w1 = __expf(lrelu(av.y + ad.y));
            float w2 = __expf(lrelu(av.z + ad.z));
            float w3 = __expf(lrelu(av.w + ad.w));
            float sf = __int_as_float(s);
            sw[0 * SWSTR + lane] = make_float2(sf, w0);
            sw[1 * SWSTR + lane] = make_float2(sf, w1);
            sw[2 * SWSTR + lane] = make_float2(sf, w2);
            sw[3 * SWSTR + lane] = make_float2(sf, w3);
        }
        int iters = (cnt + 3) >> 2;
        bool ok = sub < cnt;
        float2 sv = sw[h * SWSTR + (ok ? sub : 0)];
        float wj = ok ? sv.y : 0.f;
        unsigned row = ok ? ((unsigned)__float_as_int(sv.x) << 8) : 0u;
        uint4 v = *(const uint4*)(xwp + row);
        for (int it = 1; it <= iters; ++it) {
            int j1 = (it << 2) + sub;
            bool ok1 = j1 < cnt;
            float2 sv1 = sw[h * SWSTR + (ok1 ? j1 : 0)];
            float w1 = ok1 ? sv1.y : 0.f;
            unsigned row1 = ok1 ? ((unsigned)__float_as_int(sv1.x) << 8) : 0u;
            uint4 v1 = *(const uint4*)(xwp + row1);
            dloc += wj;
            accA.x = fmaf(wj, __uint_as_float(v.x << 16), accA.x);
            accA.y = fmaf(wj, __uint_as_float(v.x & 0xffff0000u), accA.y);
            accA.z = fmaf(wj, __uint_as_float(v.y << 16), accA.z);
            accA.w = fmaf(wj, __uint_as_float(v.y & 0xffff0000u), accA.w);
            accB.x = fmaf(wj, __uint_as_float(v.z << 16), accB.x);
            accB.y = fmaf(wj, __uint_as_float(v.z & 0xffff0000u), accB.y);
            accB.z = fmaf(wj, __uint_as_float(v.w << 16), accB.z);
            accB.w = fmaf(wj, __uint_as_float(v.w & 0xffff0000u), accB.w);
            v = v1; wj = w1;
        }
    }
#pragma unroll
    for (int off = 16; off <= 32; off <<= 1) {
        accA.x += __shfl_xor(accA.x, off);
        accA.y += __shfl_xor(accA.y, off);
        accA.z += __shfl_xor(accA.z, off);
        accA.w += __shfl_xor(accA.w, off);
        accB.x += __shfl_xor(accB.x, off);
        accB.y += __shfl_xor(accB.y, off);
        accB.z += __shfl_xor(accB.z, off);
        accB.w += __shfl_xor(accB.w, off);
        dloc += __shfl_xor(dloc, off);
    }
    if (sub == 0) {
        float inv = 1.f / dloc;
        float4 bb0 = ((const float4*)bias)[c8 * 2];
        float4 bb1 = ((const float4*)bias)[c8 * 2 + 1];
        float4 oA, oB;
        oA.x = fmaf(accA.x, inv, bb0.x);
        oA.y = fmaf(accA.y, inv, bb0.y);
        oA.z = fmaf(accA.z, inv, bb0.z);
        oA.w = fmaf(accA.w, inv, bb0.w);
        oB.x = fmaf(accB.x, inv, bb1.x);
        oB.y = fmaf(accB.y, inv, bb1.y);
        oB.z = fmaf(accB.z, inv, bb1.z);
        oB.w = fmaf(accB.w, inv, bb1.w);
        oA.x = oA.x > 0.f ? oA.x : expm1f(oA.x);
        oA.y = oA.y > 0.f ? oA.y : expm1f(oA.y);
        oA.z = oA.z > 0.f ? oA.z : expm1f(oA.z);
        oA.w = oA.w > 0.f ? oA.w : expm1f(oA.w);
        oB.x = oB.x > 0.f ? oB.x : expm1f(oB.x);
        oB.y = oB.y > 0.f ? oB.y : expm1f(oB.y);
        oB.z = oB.z > 0.f ? oB.z : expm1f(oB.z);
        oB.w = oB.w > 0.f ? oB.w : expm1f(oB.w);
        ((float4*)out)[(size_t)node * 32 + c8 * 2] = oA;
        ((float4*)out)[(size_t)node * 32 + c8 * 2 + 1] = oB;
    }
}

// ---------------- pooling + head ----------------
__global__ __launch_bounds__(128) void pool(
    const float* __restrict__ h1, const int* __restrict__ batch,
    float* __restrict__ sums, float* __restrict__ cnts) {
    int j = threadIdx.x;
    int n0 = blockIdx.x * 64;
    int n1 = n0 + 64; if (n1 > NN) n1 = NN;
    if (n0 >= NN) return;
    int cur = batch[n0];
    float local = 0.f;
    int cnt = 0;
    for (int n = n0; n < n1; ++n) {
        int g = batch[n];
        if (g != cur) {
            atomicAdd(&sums[cur * HC + j], local);
            if (j == 0) atomicAdd(&cnts[cur], (float)cnt);
            local = 0.f; cnt = 0; cur = g;
        }
        local += h1[(size_t)n * HC + j];
        ++cnt;
    }
    atomicAdd(&sums[cur * HC + j], local);
    if (j == 0) atomicAdd(&cnts[cur], (float)cnt);
}

__global__ __launch_bounds__(128) void head_out(
    const float* __restrict__ sums, const float* __restrict__ cnts,
    const float* __restrict__ lin_w, const float* __restrict__ lin_b,
    float* __restrict__ out) {
    int g = blockIdx.x;
    int j = threadIdx.x;
    float c = cnts[g];
    c = c > 1.f ? c : 1.f;
    float v = sums[g * HC + j] / c * lin_w[j];
    __shared__ float red[HC];
    red[j] = v;
    __syncthreads();
    for (int off = 64; off > 0; off >>= 1) {
        if (j < off) red[j] += red[j + off];
        __syncthreads();
    }
    if (j == 0) out[g] = red[0] + lin_b[0];
}

extern "C" void kernel_launch(void* const* d_in, const int* in_sizes, int n_in,
                              void* d_out, int out_size, void* d_ws, size_t ws_size,
                              hipStream_t stream) {
    const float* x   = (const float*)d_in[0];
    const int*   ei  = (const int*)d_in[1];
    const int*   bat = (const int*)d_in[2];
    const float* W0  = (const float*)d_in[3];
    const float* as0 = (const float*)d_in[4];
    const float* ad0 = (const float*)d_in[5];
    const float* b0  = (const float*)d_in[6];
    const float* W1  = (const float*)d_in[7];
    const float* as1 = (const float*)d_in[8];
    const float* ad1 = (const float*)d_in[9];
    const float* b1  = (const float*)d_in[10];
    const float* lw  = (const float*)d_in[11];
    const float* lb  = (const float*)d_in[12];
    float* out = (float*)d_out;

    char* w = (char*)d_ws;
    unsigned* xwb = (unsigned*)w; w += (size_t)NN * HC * 2;   // 12.8 MB bf16
    float* h0  = (float*)w;  w += (size_t)NN * HC * 4;        // 25.6 MB
    float* as_ = (float*)w;  w += (size_t)NN * HH * 4;
    float* ad_ = (float*)w;  w += (size_t)NN * HH * 4;
    int* row_start = (int*)w; w += (size_t)(NN + 1) * 4;
    int* bcur      = (int*)w; w += (size_t)NBKT * 4;
    int* esrc      = (int*)w; w += (size_t)NEDGE * 4;         // 6.6 MB
    unsigned* pairs = (unsigned*)w; w += (size_t)NBKT * BCAP * 4; // 9.8 MB
    float* sums = (float*)w; w += (size_t)GG * HC * 4;
    float* cnts = (float*)w; w += (size_t)GG * 4;

    const int ab = (NN + 3) / 4;

    // ---- binit, then merged {gemm L0 || bucketize} ----
    binit<<<1, 256, 0, stream>>>(bcur);
    g0bkt<<<NB1 * 3, 256, 0, stream>>>(x, W0, as0, ad0, xwb, as_, ad_,
                                       ei, bcur, pairs);
    debucket<<<NBKT, 512, 0, stream>>>(pairs, bcur, row_start, esrc);

    // ---- layer 0 aggregate ----
    aggregate<<<ab, 256, 0, stream>>>(esrc, row_start, as_, ad_, xwb, b0, h0);

    // ---- layer 1 ----
    gemm_alpha<<<GB, 256, 0, stream>>>(h0, W1, as1, ad1, xwb, as_, ad_);
    aggregate<<<ab, 256, 0, stream>>>(esrc, row_start, as_, ad_, xwb, b1, h0);

    // ---- pool + head ----
    hipMemsetAsync(sums, 0, ((size_t)GG * HC + GG) * 4, stream);
    pool<<<(NN + 63) / 64, 128, 0, stream>>>(h0, bat, sums, cnts);
    head_out<<<GG, 128, 0, stream>>>(sums, cnts, lw, lb, out);
}